// Round 4
// baseline (623.776 us; speedup 1.0000x reference)
//
#include <hip/hip_runtime.h>

#define N_SRC 50000
#define N_DST 50000
#define N_EDGES 1600000
#define D_NEIGH 128
#define D_SELF 128
#define D_EDGE 32
#define D_OUT 256
#define K_TOT 288   // [0,128)=self, [128,288)=hn
#define D_HN 160

// ---------------- CSR construction ----------------

__global__ void k_deg(const int* __restrict__ dst, int* __restrict__ deg, int n) {
    int i = blockIdx.x * blockDim.x + threadIdx.x;
    if (i < n) atomicAdd(&deg[dst[i]], 1);
}

__global__ __launch_bounds__(1024) void k_scan(const int* __restrict__ deg,
                                               int* __restrict__ row_start,
                                               int* __restrict__ cursor) {
    __shared__ int part[1024];
    const int t = threadIdx.x;
    const int CH = (N_DST + 1023) / 1024;  // 49
    const int b = t * CH;
    int s = 0;
    for (int i = 0; i < CH; i++) {
        int idx = b + i;
        if (idx < N_DST) s += deg[idx];
    }
    part[t] = s;
    __syncthreads();
    for (int off = 1; off < 1024; off <<= 1) {
        int v = (t >= off) ? part[t - off] : 0;
        __syncthreads();
        part[t] += v;
        __syncthreads();
    }
    int ex = (t == 0) ? 0 : part[t - 1];
    for (int i = 0; i < CH; i++) {
        int idx = b + i;
        if (idx < N_DST) {
            row_start[idx] = ex;
            cursor[idx] = ex;
            ex += deg[idx];
        }
    }
    if (t == 1023) row_start[N_DST] = part[1023];
}

// fill CSR: one packed int2(eid, src) scatter per edge (one cache line touch
// instead of two separate arrays).
template <bool PACKED>
__global__ void k_fill(const int* __restrict__ dst, const int* __restrict__ src,
                       int* __restrict__ cursor,
                       int2* __restrict__ pk, int* __restrict__ eids, int n) {
    int i = blockIdx.x * blockDim.x + threadIdx.x;
    if (i < n) {
        int p = atomicAdd(&cursor[dst[i]], 1);
        if (PACKED) pk[p] = make_int2(i, src[i]);
        else eids[p] = i;
    }
}

// ---------------- Aggregation: one wave per dst node ----------------

template <bool PACKED>
__global__ __launch_bounds__(64) void k_agg(const int* __restrict__ row_start,
                                            const int2* __restrict__ pk,
                                            const int* __restrict__ eids,
                                            const int* __restrict__ src,
                                            const float* __restrict__ h_neigh,
                                            const float* __restrict__ ef,
                                            float* __restrict__ hn) {
    const int d = blockIdx.x;
    const int lane = threadIdx.x;
    const int start = row_start[d];
    const int end = row_start[d + 1];
    const int deg = end - start;
    float ax = 0.f, ay = 0.f, ae = 0.f;
    const float* hbase = h_neigh + 2 * lane;
    const float* ebase = ef + (lane & 31);
    const int g = lane >> 5;

    for (int c = start; c < end; c += 64) {
        const int rem = end - c;
        const int m = rem < 64 ? rem : 64;
        int e = 0, s = 0;
        if (lane < m) {
            if (PACKED) { int2 p = pk[c + lane]; e = p.x; s = p.y; }  // coalesced 8B
            else        { e = eids[c + lane]; s = src[e]; }
        }
        int i = 0;
        for (; i + 8 <= m; i += 8) {
            float2 t[8];
            float te[4];
#pragma unroll
            for (int j = 0; j < 8; j++) {
                const int si = __builtin_amdgcn_readlane(s, i + j);
                t[j] = *(const float2*)(hbase + (size_t)si * D_NEIGH);
            }
#pragma unroll
            for (int j = 0; j < 4; j++) {
                const int ee = __shfl(e, i + 2 * j + g);   // lanes 0-31 even edge, 32-63 odd
                te[j] = ebase[(size_t)ee * D_EDGE];
            }
#pragma unroll
            for (int j = 0; j < 8; j++) { ax += t[j].x; ay += t[j].y; }
#pragma unroll
            for (int j = 0; j < 4; j++) ae += te[j];
        }
        for (; i < m; ++i) {
            const int si = __builtin_amdgcn_readlane(s, i);
            const int ei = __builtin_amdgcn_readlane(e, i);
            const float2 v = *(const float2*)(hbase + (size_t)si * D_NEIGH);
            ax += v.x; ay += v.y;
            if (lane < D_EDGE) ae += ef[(size_t)ei * D_EDGE + lane];
        }
    }

    ae += __shfl_xor(ae, 32);

    const float inv = 1.0f / (float)(deg > 0 ? deg : 1);
    float* o = hn + (size_t)d * D_HN;
    *(float2*)(o + 2 * lane) = make_float2(ax * inv, ay * inv);
    if (lane < D_EDGE) o[128 + lane] = ae * inv;
}

// ---------------- Fused GEMM + ReLU + row-L2-norm ----------------
// z = relu([h_self|hn] @ [W_self|W_neigh]^T); out = z / ||z||_row
// Block: 64 rows x 256 cols (full output width -> norm in-block).
// 1024 threads, micro 4x4. ty = tid>>6 is wave-uniform: Xs read is a
// broadcast, Ws read is lane-consecutive float4 (conflict-free), and the
// row sum-of-squares reduces within a single wave (shfl only).

__global__ __launch_bounds__(1024) void k_gemm_norm(const float* __restrict__ h_self,
                                                    const float* __restrict__ hn,
                                                    const float* __restrict__ Wself,
                                                    const float* __restrict__ Wneigh,
                                                    float* __restrict__ out) {
    __shared__ float Xs[32][64 + 4];
    __shared__ float Ws[32][256 + 4];
    __shared__ float rss[64];
    const int tid = threadIdx.x;
    const int tx = tid & 63;          // lane: 4 cols at tx*4
    const int ty = tid >> 6;          // wave id: 4 rows at ty*4 (uniform per wave)
    const int brow = blockIdx.x * 64;

    const int xlm = tid >> 4;          // X row 0..63
    const int xkq = (tid & 15) * 2;    // X k-pair
    const int wc = tid & 255;          // W col 0..255
    const int wk = (tid >> 8) * 8;     // W k-oct (uniform per wave)

    float acc[4][4] = {};

    for (int k0 = 0; k0 < K_TOT; k0 += 32) {
        {   // X tile: 64 rows x 32 k
            const int gm = brow + xlm;
            const int k = k0 + xkq;
            float2 v = make_float2(0.f, 0.f);
            if (gm < N_DST) {
                if (k < 128) v = *(const float2*)(h_self + (size_t)gm * D_SELF + k);
                else         v = *(const float2*)(hn + (size_t)gm * D_HN + (k - 128));
            }
            Xs[xkq][xlm] = v.x;
            Xs[xkq + 1][xlm] = v.y;
        }
        {   // W tile: 256 cols x 32 k
            const int k = k0 + wk;
            const float* wp;
            int kk;
            if (k < 128) { wp = Wself + (size_t)wc * D_SELF;  kk = k; }
            else         { wp = Wneigh + (size_t)wc * D_HN;   kk = k - 128; }
            float4 w0 = *(const float4*)(wp + kk);
            float4 w1 = *(const float4*)(wp + kk + 4);
            Ws[wk + 0][wc] = w0.x; Ws[wk + 1][wc] = w0.y;
            Ws[wk + 2][wc] = w0.z; Ws[wk + 3][wc] = w0.w;
            Ws[wk + 4][wc] = w1.x; Ws[wk + 5][wc] = w1.y;
            Ws[wk + 6][wc] = w1.z; Ws[wk + 7][wc] = w1.w;
        }
        __syncthreads();
#pragma unroll
        for (int k = 0; k < 32; k++) {
            float4 x = *(const float4*)&Xs[k][ty * 4];   // wave-uniform broadcast
            float4 w = *(const float4*)&Ws[k][tx * 4];   // lane-consecutive, conflict-free
            float xr[4] = {x.x, x.y, x.z, x.w};
            float wcv[4] = {w.x, w.y, w.z, w.w};
#pragma unroll
            for (int r = 0; r < 4; r++)
#pragma unroll
                for (int c = 0; c < 4; c++)
                    acc[r][c] = fmaf(xr[r], wcv[c], acc[r][c]);
        }
        __syncthreads();
    }

    // relu + per-row sum of squares (wave-local reduce; ty uniform per wave)
    float ssr[4];
#pragma unroll
    for (int r = 0; r < 4; r++) {
        float s = 0.f;
#pragma unroll
        for (int c = 0; c < 4; c++) {
            float z = fmaxf(acc[r][c], 0.f);
            acc[r][c] = z;
            s += z * z;
        }
        ssr[r] = s;
    }
#pragma unroll
    for (int off = 32; off; off >>= 1)
#pragma unroll
        for (int r = 0; r < 4; r++) ssr[r] += __shfl_xor(ssr[r], off);
    if (tx == 0) {
#pragma unroll
        for (int r = 0; r < 4; r++) rss[ty * 4 + r] = ssr[r];
    }
    __syncthreads();

#pragma unroll
    for (int r = 0; r < 4; r++) {
        const int row = brow + ty * 4 + r;
        if (row < N_DST) {
            const float n = sqrtf(rss[ty * 4 + r]);
            const float inv = (n == 0.f) ? 1.f : 1.f / n;
            float4 o = make_float4(acc[r][0] * inv, acc[r][1] * inv,
                                   acc[r][2] * inv, acc[r][3] * inv);
            *(float4*)&out[(size_t)row * D_OUT + tx * 4] = o;
        }
    }
}

// ---------------- launch ----------------

extern "C" void kernel_launch(void* const* d_in, const int* in_sizes, int n_in,
                              void* d_out, int out_size, void* d_ws, size_t ws_size,
                              hipStream_t stream) {
    const float* h_neigh = (const float*)d_in[0];
    const float* h_self  = (const float*)d_in[1];
    const float* ef      = (const float*)d_in[2];
    const int*   src     = (const int*)d_in[3];
    const int*   dst     = (const int*)d_in[4];
    const float* Wself   = (const float*)d_in[5];
    const float* Wneigh  = (const float*)d_in[6];
    float* out = (float*)d_out;

    char* ws = (char*)d_ws;
    int* deg       = (int*)(ws + 0);          // 50000 ints
    int* row_start = (int*)(ws + 262144);     // 50001 ints
    int* cursor    = (int*)(ws + 524288);     // 50000 ints

    const size_t need_big = 786432 + (size_t)N_EDGES * 8 + 32000000;  // ~45.6 MB
    const bool big = ws_size >= need_big;
    int2* pk;
    int* eids;
    float* hn;
    if (big) {
        pk   = (int2*)(ws + 786432);          // 1.6M int2 (12.8 MB), ends 13586432
        eids = (int*)(ws + 786432);           // unused
        hn   = (float*)(ws + 13586432);       // 32 MB
    } else {
        pk   = (int2*)(ws + 786432);          // unused
        eids = (int*)(ws + 786432);           // 1.6M ints
        hn   = (float*)(ws + 8388608);
    }

    hipMemsetAsync(deg, 0, N_DST * sizeof(int), stream);
    k_deg<<<(N_EDGES + 255) / 256, 256, 0, stream>>>(dst, deg, N_EDGES);
    k_scan<<<1, 1024, 0, stream>>>(deg, row_start, cursor);
    if (big) {
        k_fill<true><<<(N_EDGES + 255) / 256, 256, 0, stream>>>(dst, src, cursor, pk, eids, N_EDGES);
        k_agg<true><<<N_DST, 64, 0, stream>>>(row_start, pk, eids, src, h_neigh, ef, hn);
    } else {
        k_fill<false><<<(N_EDGES + 255) / 256, 256, 0, stream>>>(dst, src, cursor, pk, eids, N_EDGES);
        k_agg<false><<<N_DST, 64, 0, stream>>>(row_start, pk, eids, src, h_neigh, ef, hn);
    }

    k_gemm_norm<<<(N_DST + 63) / 64, 1024, 0, stream>>>(h_self, hn, Wself, Wneigh, out);
}

// Round 5
// 452.709 us; speedup vs baseline: 1.3779x; 1.3779x over previous
//
#include <hip/hip_runtime.h>

#define N_SRC 50000
#define N_DST 50000
#define N_EDGES 1600000
#define D_NEIGH 128
#define D_SELF 128
#define D_EDGE 32
#define D_OUT 256
#define K_TOT 288   // [0,128)=self(f32 src), [128,288)=hn(bf16 in hnb)
#define D_HN 160

typedef float f32x4 __attribute__((ext_vector_type(4)));
typedef short s16x8 __attribute__((ext_vector_type(8)));

__device__ __forceinline__ ushort f2bf(float x) {
    unsigned b = __float_as_uint(x);
    return (ushort)((b + 0x7fffu + ((b >> 16) & 1u)) >> 16);  // RNE
}
__device__ __forceinline__ float bflo(unsigned u) { return __uint_as_float(u << 16); }
__device__ __forceinline__ float bfhi(unsigned u) { return __uint_as_float(u & 0xffff0000u); }

// ---------------- CSR construction ----------------

__global__ void k_deg(const int* __restrict__ dst, int* __restrict__ deg, int n) {
    int i = blockIdx.x * blockDim.x + threadIdx.x;
    if (i < n) atomicAdd(&deg[dst[i]], 1);
}

__global__ __launch_bounds__(1024) void k_scan(const int* __restrict__ deg,
                                               int* __restrict__ row_start,
                                               int* __restrict__ cursor) {
    __shared__ int part[1024];
    const int t = threadIdx.x;
    const int CH = (N_DST + 1023) / 1024;  // 49
    const int b = t * CH;
    int s = 0;
    for (int i = 0; i < CH; i++) {
        int idx = b + i;
        if (idx < N_DST) s += deg[idx];
    }
    part[t] = s;
    __syncthreads();
    for (int off = 1; off < 1024; off <<= 1) {
        int v = (t >= off) ? part[t - off] : 0;
        __syncthreads();
        part[t] += v;
        __syncthreads();
    }
    int ex = (t == 0) ? 0 : part[t - 1];
    for (int i = 0; i < CH; i++) {
        int idx = b + i;
        if (idx < N_DST) {
            row_start[idx] = ex;
            cursor[idx] = ex;
            ex += deg[idx];
        }
    }
    if (t == 1023) row_start[N_DST] = part[1023];
}

__global__ void k_fill(const int* __restrict__ dst, const int* __restrict__ src,
                       int* __restrict__ cursor, int2* __restrict__ pk, int n) {
    int i = blockIdx.x * blockDim.x + threadIdx.x;
    if (i < n) {
        int p = atomicAdd(&cursor[dst[i]], 1);
        pk[p] = make_int2(i, src[i]);
    }
}

// ---------------- h_neigh f32 -> bf16 (halves gather volume in k_agg) -------

__global__ void k_cvt(const float* __restrict__ in, ushort* __restrict__ out, int n4) {
    int i = blockIdx.x * blockDim.x + threadIdx.x;
    if (i < n4) {
        float4 f = ((const float4*)in)[i];
        ushort4 v = make_ushort4(f2bf(f.x), f2bf(f.y), f2bf(f.z), f2bf(f.w));
        ((ushort4*)out)[i] = v;
    }
}

// ---------------- Aggregation: one wave per dst node ----------------
// Writes the per-dst mean directly as bf16 into hnb[50000][160] (GEMM X cols
// 128..287). HB: gather bf16 rows from hb (256B/row) else f32 (512B/row).

template <bool HB>
__global__ __launch_bounds__(64) void k_agg(const int* __restrict__ row_start,
                                            const int2* __restrict__ pk,
                                            const ushort* __restrict__ hb,
                                            const float* __restrict__ h_neigh,
                                            const float* __restrict__ ef,
                                            ushort* __restrict__ hnb) {
    const int d = blockIdx.x;
    const int lane = threadIdx.x;
    const int start = row_start[d];
    const int end = row_start[d + 1];
    const int deg = end - start;
    float ax = 0.f, ay = 0.f, ae = 0.f;
    const float* ebase = ef + (lane & 31);
    const int g = lane >> 5;

    for (int c = start; c < end; c += 64) {
        const int rem = end - c;
        const int m = rem < 64 ? rem : 64;
        int e = 0, s = 0;
        if (lane < m) { int2 p = pk[c + lane]; e = p.x; s = p.y; }
        int i = 0;
        for (; i + 8 <= m; i += 8) {
            unsigned u[8];
            float2 t[8];
            float te[4];
#pragma unroll
            for (int j = 0; j < 8; j++) {
                const int si = __builtin_amdgcn_readlane(s, i + j);
                if (HB) u[j] = *(const unsigned*)(hb + (size_t)si * D_NEIGH + 2 * lane);
                else    t[j] = *(const float2*)(h_neigh + (size_t)si * D_NEIGH + 2 * lane);
            }
#pragma unroll
            for (int j = 0; j < 4; j++) {
                const int ee = __shfl(e, i + 2 * j + g);   // lanes 0-31 even, 32-63 odd
                te[j] = ebase[(size_t)ee * D_EDGE];
            }
#pragma unroll
            for (int j = 0; j < 8; j++) {
                if (HB) { ax += bflo(u[j]); ay += bfhi(u[j]); }
                else    { ax += t[j].x;     ay += t[j].y;     }
            }
#pragma unroll
            for (int j = 0; j < 4; j++) ae += te[j];
        }
        for (; i < m; ++i) {
            const int si = __builtin_amdgcn_readlane(s, i);
            const int ei = __builtin_amdgcn_readlane(e, i);
            if (HB) { unsigned u = *(const unsigned*)(hb + (size_t)si * D_NEIGH + 2 * lane);
                      ax += bflo(u); ay += bfhi(u); }
            else    { float2 v = *(const float2*)(h_neigh + (size_t)si * D_NEIGH + 2 * lane);
                      ax += v.x; ay += v.y; }
            if (lane < D_EDGE) ae += ef[(size_t)ei * D_EDGE + lane];
        }
    }

    ae += __shfl_xor(ae, 32);

    const float inv = 1.0f / (float)(deg > 0 ? deg : 1);
    ushort* o = hnb + (size_t)d * D_HN;
    ushort2 w2 = make_ushort2(f2bf(ax * inv), f2bf(ay * inv));
    *(ushort2*)(o + 2 * lane) = w2;
    if (lane < D_EDGE) o[128 + lane] = f2bf(ae * inv);
}

// ---------------- Fused bf16-MFMA GEMM + ReLU + row-L2-norm ----------------
// z = relu([h_self|hn] @ [W_self|W_neigh]^T); out = z/||z||.
// Block = 64 rows x 256 cols (full width -> in-block norm), 512 threads
// (8 waves as 2x4: each wave 32 rows x 64 cols = 2x4 frags of 16x16).
// LDS tiles padded to 80B rows: b128 frag reads are 2-way conflicts (free).

__global__ __launch_bounds__(512) void k_gemm_norm(const float* __restrict__ h_self,
                                                   const ushort* __restrict__ hnb,
                                                   const float* __restrict__ Wself,
                                                   const float* __restrict__ Wneigh,
                                                   float* __restrict__ out) {
    __shared__ __align__(16) ushort Xs[64 * 40];    // 40 ushort = 80B row stride
    __shared__ __align__(16) ushort Ws[256 * 40];
    __shared__ float rsum[4][64];
    __shared__ float invn[64];

    const int tid = threadIdx.x;
    const int lane = tid & 63;
    const int wid = tid >> 6;
    const int wm = wid >> 2;          // 0..1: row block of 32
    const int wn = wid & 3;           // 0..3: col block of 64
    const int brow = blockIdx.x * 64;

    const int xrow = tid >> 3, xpart = tid & 7;    // X stage: 4 bf16 per thread
    const int wcol = tid >> 1, whalf = tid & 1;    // W stage: 16 bf16 per thread

    f32x4 acc[2][4] = {};

    for (int k0 = 0; k0 < K_TOT; k0 += 32) {
        {   // ---- X tile: 64 rows x 32 k (bf16) ----
            const int gr = brow + xrow;
            ushort4 v = make_ushort4(0, 0, 0, 0);
            if (gr < N_DST) {
                if (k0 < 128) {
                    float4 f = *(const float4*)(h_self + (size_t)gr * D_SELF + k0 + xpart * 4);
                    v = make_ushort4(f2bf(f.x), f2bf(f.y), f2bf(f.z), f2bf(f.w));
                } else {
                    v = *(const ushort4*)(hnb + (size_t)gr * D_HN + (k0 - 128) + xpart * 4);
                }
            }
            *(ushort4*)&Xs[xrow * 40 + xpart * 4] = v;
        }
        {   // ---- W tile: 256 cols x 32 k (cvt f32->bf16 in staging) ----
            const int kb = k0 + whalf * 16;
            const float* wp;
            int kk;
            if (kb < 128) { wp = Wself + (size_t)wcol * D_SELF;  kk = kb; }
            else          { wp = Wneigh + (size_t)wcol * D_HN;   kk = kb - 128; }
            float4 f0 = *(const float4*)(wp + kk);
            float4 f1 = *(const float4*)(wp + kk + 4);
            float4 f2 = *(const float4*)(wp + kk + 8);
            float4 f3 = *(const float4*)(wp + kk + 12);
            ushort4 a = make_ushort4(f2bf(f0.x), f2bf(f0.y), f2bf(f0.z), f2bf(f0.w));
            ushort4 b = make_ushort4(f2bf(f1.x), f2bf(f1.y), f2bf(f1.z), f2bf(f1.w));
            ushort4 c = make_ushort4(f2bf(f2.x), f2bf(f2.y), f2bf(f2.z), f2bf(f2.w));
            ushort4 d = make_ushort4(f2bf(f3.x), f2bf(f3.y), f2bf(f3.z), f2bf(f3.w));
            ushort* wb = &Ws[wcol * 40 + whalf * 16];
            *(ushort4*)(wb + 0) = a;  *(ushort4*)(wb + 4) = b;
            *(ushort4*)(wb + 8) = c;  *(ushort4*)(wb + 12) = d;
        }
        __syncthreads();

        s16x8 af[2], bf[4];
        const int koff = (lane >> 4) * 8;            // k-octet per 16-lane group
        const int rsel = lane & 15;
#pragma unroll
        for (int fi = 0; fi < 2; fi++)
            af[fi] = *(const s16x8*)&Xs[(wm * 32 + fi * 16 + rsel) * 40 + koff];
#pragma unroll
        for (int fj = 0; fj < 4; fj++)
            bf[fj] = *(const s16x8*)&Ws[(wn * 64 + fj * 16 + rsel) * 40 + koff];
#pragma unroll
        for (int fi = 0; fi < 2; fi++)
#pragma unroll
            for (int fj = 0; fj < 4; fj++)
                acc[fi][fj] = __builtin_amdgcn_mfma_f32_16x16x32_bf16(af[fi], bf[fj], acc[fi][fj], 0, 0, 0);
        __syncthreads();
    }

    // ---- relu + row sum-of-squares ----
    // C/D layout: col = lane&15, row = (lane>>4)*4 + reg  [guide §3, m89]
    float ss[2][4];
#pragma unroll
    for (int fi = 0; fi < 2; fi++)
#pragma unroll
        for (int j = 0; j < 4; j++) {
            float s = 0.f;
#pragma unroll
            for (int fj = 0; fj < 4; fj++) {
                float z = fmaxf(acc[fi][fj][j], 0.f);
                acc[fi][fj][j] = z;
                s += z * z;
            }
            ss[fi][j] = s;
        }
#pragma unroll
    for (int m = 1; m < 16; m <<= 1)
#pragma unroll
        for (int fi = 0; fi < 2; fi++)
#pragma unroll
            for (int j = 0; j < 4; j++) ss[fi][j] += __shfl_xor(ss[fi][j], m);
    if ((lane & 15) == 0) {
        const int gg = lane >> 4;
#pragma unroll
        for (int fi = 0; fi < 2; fi++)
#pragma unroll
            for (int j = 0; j < 4; j++)
                rsum[wn][wm * 32 + fi * 16 + gg * 4 + j] = ss[fi][j];
    }
    __syncthreads();
    if (tid < 64) {
        float t = rsum[0][tid] + rsum[1][tid] + rsum[2][tid] + rsum[3][tid];
        invn[tid] = (t > 0.f) ? 1.f / sqrtf(t) : 1.f;
    }
    __syncthreads();

#pragma unroll
    for (int fi = 0; fi < 2; fi++)
#pragma unroll
        for (int j = 0; j < 4; j++) {
            const int rl = wm * 32 + fi * 16 + (lane >> 4) * 4 + j;
            const int row = brow + rl;
            if (row < N_DST) {
                const float iv = invn[rl];
#pragma unroll
                for (int fj = 0; fj < 4; fj++)
                    out[(size_t)row * D_OUT + wn * 64 + fj * 16 + (lane & 15)] = acc[fi][fj][j] * iv;
            }
        }
}

// ---------------- launch ----------------

extern "C" void kernel_launch(void* const* d_in, const int* in_sizes, int n_in,
                              void* d_out, int out_size, void* d_ws, size_t ws_size,
                              hipStream_t stream) {
    const float* h_neigh = (const float*)d_in[0];
    const float* h_self  = (const float*)d_in[1];
    const float* ef      = (const float*)d_in[2];
    const int*   src     = (const int*)d_in[3];
    const int*   dst     = (const int*)d_in[4];
    const float* Wself   = (const float*)d_in[5];
    const float* Wneigh  = (const float*)d_in[6];
    float* out = (float*)d_out;

    char* ws = (char*)d_ws;
    int* deg       = (int*)(ws + 0);
    int* row_start = (int*)(ws + 262144);
    int* cursor    = (int*)(ws + 524288);
    int2* pk       = (int2*)(ws + 786432);            // 12.8 MB, ends 13586432

    // Tier A (needs 42.4 MB; R3 counters prove ws >= 45.6 MB): bf16 h_neigh copy.
    const size_t needA = 13586432ull + 12800000ull + 16000000ull;
    const bool hbtier = ws_size >= needA;
    ushort* hb, *hnb;
    if (hbtier) {
        hb  = (ushort*)(ws + 13586432);               // 50000x128 bf16, ends 26386432
        hnb = (ushort*)(ws + 26386432);               // 50000x160 bf16, ends 42386432
    } else {
        hb  = (ushort*)(ws + 13586432);               // unused
        hnb = (ushort*)(ws + 13586432);               // ends 29586432
    }

    hipMemsetAsync(deg, 0, N_DST * sizeof(int), stream);
    k_deg<<<(N_EDGES + 255) / 256, 256, 0, stream>>>(dst, deg, N_EDGES);
    k_scan<<<1, 1024, 0, stream>>>(deg, row_start, cursor);
    k_fill<<<(N_EDGES + 255) / 256, 256, 0, stream>>>(dst, src, cursor, pk, N_EDGES);
    if (hbtier) {
        k_cvt<<<(N_SRC * D_NEIGH / 4 + 255) / 256, 256, 0, stream>>>(h_neigh, hb, N_SRC * D_NEIGH / 4);
        k_agg<true><<<N_DST, 64, 0, stream>>>(row_start, pk, hb, h_neigh, ef, hnb);
    } else {
        k_agg<false><<<N_DST, 64, 0, stream>>>(row_start, pk, hb, h_neigh, ef, hnb);
    }
    k_gemm_norm<<<(N_DST + 63) / 64, 512, 0, stream>>>(h_self, hnb, Wself, Wneigh, out);
}